// Round 5
// baseline (17101.833 us; speedup 1.0000x reference)
//
#include <hip/hip_runtime.h>
#include <hip/hip_cooperative_groups.h>
#include <stdint.h>

namespace cg = cooperative_groups;

#define BB 64
#define DD 512
#define HH 1024
#define VV 32000
#define T_STEPS 50
#define G3 3072
#define NT 250      // logits col-tiles (128 cols each)
#define NMEGA 8     // mega-blocks in phase A (each owns 3 gate col-tiles of 128)

typedef __attribute__((ext_vector_type(8))) short bf16x8;
typedef __attribute__((ext_vector_type(4))) float f32x4;
typedef unsigned long long u64;
typedef unsigned short ushort_t;

__device__ __forceinline__ uint32_t rotl32(uint32_t x, int d) {
  return (x << d) | (x >> (32 - d));
}

// JAX threefry2x32 (20 rounds) — verified exact in rounds 1-4.
__device__ __forceinline__ void threefry2x32(uint32_t k0, uint32_t k1,
                                             uint32_t& x0, uint32_t& x1) {
  uint32_t ks0 = k0, ks1 = k1, ks2 = k0 ^ k1 ^ 0x1BD11BDAu;
  x0 += ks0; x1 += ks1;
#define TF_R(r) { x0 += x1; x1 = rotl32(x1, (r)); x1 ^= x0; }
  TF_R(13) TF_R(15) TF_R(26) TF_R(6)
  x0 += ks1; x1 += ks2 + 1u;
  TF_R(17) TF_R(29) TF_R(16) TF_R(24)
  x0 += ks2; x1 += ks0 + 2u;
  TF_R(13) TF_R(15) TF_R(26) TF_R(6)
  x0 += ks0; x1 += ks1 + 3u;
  TF_R(17) TF_R(29) TF_R(16) TF_R(24)
  x0 += ks1; x1 += ks2 + 4u;
  TF_R(13) TF_R(15) TF_R(26) TF_R(6)
  x0 += ks2; x1 += ks0 + 5u;
#undef TF_R
}

__device__ __forceinline__ uint32_t f2bf(float f) {
  uint32_t u = __float_as_uint(f);
  return (u + 0x7fffu + ((u >> 16) & 1u)) >> 16;
}
__device__ __forceinline__ float bf2f(uint32_t b) { return __uint_as_float(b << 16); }

__device__ __forceinline__ u64 packkey(float v, int c) {
  uint32_t s = __float_as_uint(v);
  uint32_t mo = (s & 0x80000000u) ? ~s : (s | 0x80000000u);
  return ((u64)mo << 32) | (uint32_t)(~(uint32_t)c);
}
__device__ __forceinline__ u64 umax64(u64 a, u64 b) { return a > b ? a : b; }

union BF8 { uint32_t u[4]; bf16x8 v; };

__device__ __forceinline__ void split8(const float* f, bf16x8& hi, bf16x8& lo) {
  BF8 H, L;
#pragma unroll
  for (int i = 0; i < 4; ++i) {
    float a = f[2 * i], b = f[2 * i + 1];
    uint32_t ha = f2bf(a), hb = f2bf(b);
    float ra = a - bf2f(ha), rb = b - bf2f(hb);
    H.u[i] = ha | (hb << 16);
    L.u[i] = f2bf(ra) | (f2bf(rb) << 16);
  }
  hi = H.v; lo = L.v;
}

__device__ __forceinline__ void split_store4(const float4 v, ushort_t* hi,
                                             ushort_t* lo, long i) {
  uint32_t h0 = f2bf(v.x), h1 = f2bf(v.y), h2 = f2bf(v.z), h3 = f2bf(v.w);
  uint32_t l0 = f2bf(v.x - bf2f(h0)), l1 = f2bf(v.y - bf2f(h1));
  uint32_t l2 = f2bf(v.z - bf2f(h2)), l3 = f2bf(v.w - bf2f(h3));
  *(uint2*)(hi + i) = make_uint2(h0 | (h1 << 16), h2 | (h3 << 16));
  *(uint2*)(lo + i) = make_uint2(l0 | (l1 << 16), l2 | (l3 << 16));
}

__device__ void split_arr(const float* __restrict__ s, ushort_t* __restrict__ hi,
                          ushort_t* __restrict__ lo, long n, long st, long stride) {
  for (long i = st; i < n; i += stride) {
    float4 v = *(const float4*)(s + i);
    split_store4(v, hi, lo, i);
  }
}

// 8-wave 64x128 tile: acc += A[64][K] @ B[n0..n0+127][K]^T.
// A: pre-split bf16 (row-major) OR fp32 with per-row gather (AGATHER).
// B: pre-split bf16 hi/lo row-major — direct 16B global loads, NO LDS.
// Same 3-term split-precision order as the verified round-2/4 kernels.
template<bool AGATHER>
__device__ __forceinline__ void tile_direct(
    const ushort_t* __restrict__ Ahi, const ushort_t* __restrict__ Alo,
    const float* __restrict__ Ag, const int* __restrict__ rowidx, int lda,
    const ushort_t* __restrict__ Bhi, const ushort_t* __restrict__ Blo,
    int K, int n0, f32x4 acc[2][2])
{
  const int tid = threadIdx.x, lane = tid & 63, w = tid >> 6;
  const int l15 = lane & 15, q = lane >> 4;
  const int rw = (w >> 2) * 32, cw = (w & 3) * 32;

  size_t abase[2], bbase[2];
#pragma unroll
  for (int m = 0; m < 2; ++m) {
    int r = rw + 16 * m + l15;
    abase[m] = (size_t)(AGATHER ? rowidx[r] : r) * lda + 8 * q;
  }
#pragma unroll
  for (int n = 0; n < 2; ++n)
    bbase[n] = (size_t)(n0 + cw + 16 * n + l15) * K + 8 * q;

  for (int k0 = 0; k0 < K; k0 += 32) {
    bf16x8 ah[2], al[2], bh[2], bl[2];
#pragma unroll
    for (int m = 0; m < 2; ++m) {
      if constexpr (AGATHER) {
        const float* ap = Ag + abase[m] + k0;
        float4 a0 = *(const float4*)ap;
        float4 a1 = *(const float4*)(ap + 4);
        float f[8] = {a0.x, a0.y, a0.z, a0.w, a1.x, a1.y, a1.z, a1.w};
        split8(f, ah[m], al[m]);
      } else {
        ah[m] = *(const bf16x8*)(Ahi + abase[m] + k0);
        al[m] = *(const bf16x8*)(Alo + abase[m] + k0);
      }
    }
#pragma unroll
    for (int n = 0; n < 2; ++n) {
      bh[n] = *(const bf16x8*)(Bhi + bbase[n] + k0);
      bl[n] = *(const bf16x8*)(Blo + bbase[n] + k0);
    }
#pragma unroll
    for (int m = 0; m < 2; ++m)
#pragma unroll
      for (int n = 0; n < 2; ++n) {
        acc[m][n] = __builtin_amdgcn_mfma_f32_16x16x32_bf16(ah[m], bh[n], acc[m][n], 0, 0, 0);
        acc[m][n] = __builtin_amdgcn_mfma_f32_16x16x32_bf16(ah[m], bl[n], acc[m][n], 0, 0, 0);
        acc[m][n] = __builtin_amdgcn_mfma_f32_16x16x32_bf16(al[m], bh[n], acc[m][n], 0, 0, 0);
      }
  }
}

__device__ __forceinline__ void store_tile512(f32x4 acc[2][2], float* __restrict__ C,
                                              int ldc, int n0)
{
  const int tid = threadIdx.x, lane = tid & 63, w = tid >> 6;
  const int l15 = lane & 15, q = lane >> 4;
  const int rw = (w >> 2) * 32, cw = (w & 3) * 32;
#pragma unroll
  for (int m = 0; m < 2; ++m)
#pragma unroll
    for (int n = 0; n < 2; ++n)
#pragma unroll
      for (int r = 0; r < 4; ++r)
        C[(size_t)(rw + 16 * m + 4 * q + r) * ldc + n0 + cw + 16 * n + l15] = acc[m][n][r];
}

// logits store(+bias) + fused gumbel-argmax partial per batch row (verified math)
__device__ __forceinline__ void sample_epi512(
    f32x4 acc[2][2], u64 (*__restrict__ scr)[4],
    const float* __restrict__ bias, float* __restrict__ C, int n0,
    u64* __restrict__ partial, int jobid, int t)
{
  const int tid = threadIdx.x, lane = tid & 63, w = tid >> 6;
  const int l15 = lane & 15, q = lane >> 4;
  const int rw = (w >> 2) * 32, cw = (w & 3) * 32;

  uint32_t kt0 = 0u, kt1 = (uint32_t)t;
  threefry2x32(0u, 42u, kt0, kt1);

  u64 bk[2][4];
#pragma unroll
  for (int m = 0; m < 2; ++m)
#pragma unroll
    for (int r = 0; r < 4; ++r) bk[m][r] = 0ull;

#pragma unroll
  for (int m = 0; m < 2; ++m)
#pragma unroll
    for (int n = 0; n < 2; ++n)
#pragma unroll
      for (int r = 0; r < 4; ++r) {
        int row = rw + 16 * m + 4 * q + r;          // batch index
        int col = n0 + cw + 16 * n + l15;           // vocab index
        float val = acc[m][n][r] + bias[col];
        C[(size_t)row * VV + col] = val;
        uint32_t c0 = 0u, c1 = (uint32_t)(row * VV + col);
        threefry2x32(kt0, kt1, c0, c1);
        uint32_t bits = c0 ^ c1;
        float u = __uint_as_float((bits >> 9) | 0x3f800000u) - 1.0f;
        if (u == 0.0f) u = 1.17549435e-38f;
        float g = -__logf(-__logf(u));
        bk[m][r] = umax64(bk[m][r], packkey(val + g, col));
      }
#pragma unroll
  for (int off = 1; off < 16; off <<= 1)
#pragma unroll
    for (int m = 0; m < 2; ++m)
#pragma unroll
      for (int r = 0; r < 4; ++r)
        bk[m][r] = umax64(bk[m][r], (u64)__shfl_xor((long long)bk[m][r], off, 64));

  if (l15 == 0) {
#pragma unroll
    for (int m = 0; m < 2; ++m)
#pragma unroll
      for (int r = 0; r < 4; ++r)
        scr[rw + 16 * m + 4 * q + r][w & 3] = bk[m][r];
  }
  __syncthreads();
  if (tid < 64) {
    u64 f = umax64(umax64(scr[tid][0], scr[tid][1]),
                   umax64(scr[tid][2], scr[tid][3]));
    partial[(size_t)tid * NT + jobid] = f;
  }
  __syncthreads();
}

// Phase A (8 mega-blocks): finish(t-1) -> idx; gi = emb[idx]@Wih^T (3 tiles);
// gh = h_old@Whh^T (3 tiles); block-local GRU fuse of hidden cols [mb*128,+128).
__device__ __forceinline__ void stepA(
    int mb, int t,
    const float* __restrict__ emb, const float* __restrict__ bih,
    const float* __restrict__ bhh, int eosv, float* __restrict__ idx_out,
    const float* __restrict__ hOld,
    const ushort_t* __restrict__ hhiOld, const ushort_t* __restrict__ hloOld,
    float* __restrict__ hNew,
    ushort_t* __restrict__ hhiNew, ushort_t* __restrict__ hloNew,
    float* __restrict__ gi, float* __restrict__ gh,
    const u64* __restrict__ partial,
    const ushort_t* __restrict__ wihH, const ushort_t* __restrict__ wihL,
    const ushort_t* __restrict__ whhH, const ushort_t* __restrict__ whhL,
    u64 (*__restrict__ fin)[8], int* __restrict__ idxS)
{
  const int tid = threadIdx.x;
  if (t > 0) {
    const int row = tid >> 3, sub = tid & 7;
    u64 best = 0;
    for (int i = sub; i < NT; i += 8)
      best = umax64(best, partial[(size_t)row * NT + i]);
    fin[row][sub] = best;
    __syncthreads();
    if (tid < 64) {
      u64 b2 = fin[tid][0];
#pragma unroll
      for (int s = 1; s < 8; ++s) b2 = umax64(b2, fin[tid][s]);
      int idx = (int)(~(uint32_t)b2);
      idxS[tid] = idx;
      if (mb == 0) idx_out[(size_t)(t - 1) * BB + tid] = (float)idx;
    }
    __syncthreads();
  } else {
    if (tid < 64) idxS[tid] = eosv;
    __syncthreads();
  }
  if (t == T_STEPS) return;

  for (int g = 0; g < 3; ++g) {
    int n0 = mb * 128 + g * 1024;
    f32x4 acc[2][2] = {};
    tile_direct<true>(nullptr, nullptr, emb, idxS, DD, wihH, wihL, DD, n0, acc);
    store_tile512(acc, gi, G3, n0);
  }
  for (int g = 0; g < 3; ++g) {
    int n0 = mb * 128 + g * 1024;
    f32x4 acc[2][2] = {};
    tile_direct<false>(hhiOld, hloOld, nullptr, nullptr, HH, whhH, whhL, HH, n0, acc);
    store_tile512(acc, gh, G3, n0);
  }
  __threadfence_block();
  __syncthreads();

  for (int e = tid; e < 64 * 128; e += 512) {
    int b = e >> 7, j = mb * 128 + (e & 127);
    const float* gir = gi + (size_t)b * G3;
    const float* ghr = gh + (size_t)b * G3;
    float ir  = gir[j]        + bih[j],        hr = ghr[j]        + bhh[j];
    float iz  = gir[j + 1024] + bih[j + 1024], hz = ghr[j + 1024] + bhh[j + 1024];
    float in_ = gir[j + 2048] + bih[j + 2048], hn = ghr[j + 2048] + bhh[j + 2048];
    float r = 1.f / (1.f + expf(-(ir + hr)));
    float z = 1.f / (1.f + expf(-(iz + hz)));
    float n = tanhf(in_ + r * hn);
    int i = b * HH + j;
    float hv = (1.f - z) * n + z * hOld[i];
    hNew[i] = hv;
    uint32_t hb = f2bf(hv);
    hhiNew[i] = (ushort_t)hb;
    hloNew[i] = (ushort_t)f2bf(hv - bf2f(hb));
  }
}

__device__ __forceinline__ void stepB(
    int job, int t,
    const ushort_t* __restrict__ hhi, const ushort_t* __restrict__ hlo,
    const ushort_t* __restrict__ fcwH, const ushort_t* __restrict__ fcwL,
    const float* __restrict__ fcb, float* __restrict__ lg,
    u64* __restrict__ partial, u64 (*__restrict__ scr)[4])
{
  f32x4 acc[2][2] = {};
  tile_direct<false>(hhi, hlo, nullptr, nullptr, HH, fcwH, fcwL, HH, job * 128, acc);
  sample_epi512(acc, scr, fcb, lg, job * 128, partial, job, t);
}

__device__ __forceinline__ void prologue_body(
    const float* __restrict__ seq, const float* __restrict__ Wih,
    const float* __restrict__ Whh, const float* __restrict__ fcw,
    float* __restrict__ h0, ushort_t* __restrict__ h0hi, ushort_t* __restrict__ h0lo,
    ushort_t* __restrict__ wihH, ushort_t* __restrict__ wihL,
    ushort_t* __restrict__ whhH, ushort_t* __restrict__ whhL,
    ushort_t* __restrict__ fcwH, ushort_t* __restrict__ fcwL)
{
  long st = 4L * ((long)blockIdx.x * blockDim.x + threadIdx.x);
  long stride = 4L * (long)gridDim.x * blockDim.x;
  split_arr(Wih, wihH, wihL, (long)G3 * DD, st, stride);
  split_arr(Whh, whhH, whhL, (long)G3 * HH, st, stride);
  split_arr(fcw, fcwH, fcwL, (long)VV * HH, st, stride);
  for (long i = st; i < BB * HH; i += stride) {
    float4 v = *(const float4*)(seq + i);
    *(float4*)(h0 + i) = v;
    split_store4(v, h0hi, h0lo, i);
  }
}

// ---------------- cooperative mega-kernel ----------------
__global__ __launch_bounds__(512, 2) void decoder_all(
    const float* __restrict__ seq, const float* __restrict__ emb,
    const float* __restrict__ Wih, const float* __restrict__ Whh,
    const float* __restrict__ bih, const float* __restrict__ bhh,
    const float* __restrict__ fcw, const float* __restrict__ fcb,
    const int* __restrict__ eos,
    float* __restrict__ idx_out, float* __restrict__ log_out,
    float* __restrict__ hbuf, ushort_t* __restrict__ hhibuf,
    ushort_t* __restrict__ hlobuf,
    float* __restrict__ gi, float* __restrict__ gh, u64* __restrict__ partial,
    ushort_t* __restrict__ wihH, ushort_t* __restrict__ wihL,
    ushort_t* __restrict__ whhH, ushort_t* __restrict__ whhL,
    ushort_t* __restrict__ fcwH, ushort_t* __restrict__ fcwL)
{
  cg::grid_group grid = cg::this_grid();
  __shared__ u64 scr[64][4];
  __shared__ u64 fin[64][8];
  __shared__ int idxS[64];
  const int bid = blockIdx.x, GRD = gridDim.x;
  const int eosv = eos[0];

  prologue_body(seq, Wih, Whh, fcw, hbuf, hhibuf, hlobuf,
                wihH, wihL, whhH, whhL, fcwH, fcwL);
  grid.sync();

  for (int t = 0; t <= T_STEPS; ++t) {
    const int rb = t & 1, wb = rb ^ 1;
    if (bid < NMEGA)
      stepA(bid, t, emb, bih, bhh, eosv, idx_out,
            hbuf + (size_t)rb * BB * HH,
            hhibuf + (size_t)rb * BB * HH, hlobuf + (size_t)rb * BB * HH,
            hbuf + (size_t)wb * BB * HH,
            hhibuf + (size_t)wb * BB * HH, hlobuf + (size_t)wb * BB * HH,
            gi, gh, partial, wihH, wihL, whhH, whhL, fin, idxS);
    if (t == T_STEPS) break;
    grid.sync();
    for (int job = bid; job < NT; job += GRD)
      stepB(job, t, hhibuf + (size_t)wb * BB * HH, hlobuf + (size_t)wb * BB * HH,
            fcwH, fcwL, fcb, log_out + (size_t)t * BB * VV, partial, scr);
    grid.sync();
  }
}

// ---------------- multi-launch fallback (same device helpers) ----------------
__global__ __launch_bounds__(512) void k_pro(
    const float* seq, const float* Wih, const float* Whh, const float* fcw,
    float* hbuf, ushort_t* hhibuf, ushort_t* hlobuf,
    ushort_t* wihH, ushort_t* wihL, ushort_t* whhH, ushort_t* whhL,
    ushort_t* fcwH, ushort_t* fcwL)
{
  prologue_body(seq, Wih, Whh, fcw, hbuf, hhibuf, hlobuf,
                wihH, wihL, whhH, whhL, fcwH, fcwL);
}

__global__ __launch_bounds__(512, 2) void k_A(
    int t, const float* emb, const float* bih, const float* bhh,
    const int* eos, float* idx_out,
    float* hbuf, ushort_t* hhibuf, ushort_t* hlobuf,
    float* gi, float* gh, const u64* partial,
    const ushort_t* wihH, const ushort_t* wihL,
    const ushort_t* whhH, const ushort_t* whhL)
{
  __shared__ u64 fin[64][8];
  __shared__ int idxS[64];
  const int rb = t & 1, wb = rb ^ 1;
  stepA(blockIdx.x, t, emb, bih, bhh, eos[0], idx_out,
        hbuf + (size_t)rb * BB * HH,
        hhibuf + (size_t)rb * BB * HH, hlobuf + (size_t)rb * BB * HH,
        hbuf + (size_t)wb * BB * HH,
        hhibuf + (size_t)wb * BB * HH, hlobuf + (size_t)wb * BB * HH,
        gi, gh, partial, wihH, wihL, whhH, whhL, fin, idxS);
}

__global__ __launch_bounds__(512, 2) void k_B(
    int t, const ushort_t* hhibuf, const ushort_t* hlobuf,
    const ushort_t* fcwH, const ushort_t* fcwL, const float* fcb,
    float* log_out, u64* partial)
{
  __shared__ u64 scr[64][4];
  const int wb = (t & 1) ^ 1;
  stepB(blockIdx.x, t, hhibuf + (size_t)wb * BB * HH,
        hlobuf + (size_t)wb * BB * HH, fcwH, fcwL, fcb,
        log_out + (size_t)t * BB * VV, partial, scr);
}

extern "C" void kernel_launch(void* const* d_in, const int* in_sizes, int n_in,
                              void* d_out, int out_size, void* d_ws, size_t ws_size,
                              hipStream_t stream) {
  const float* seq = (const float*)d_in[0];
  const float* emb = (const float*)d_in[1];
  const float* Wih = (const float*)d_in[2];
  const float* Whh = (const float*)d_in[3];
  const float* bih = (const float*)d_in[4];
  const float* bhh = (const float*)d_in[5];
  const float* fcw = (const float*)d_in[6];
  const float* fcb = (const float*)d_in[7];
  const int*   eos = (const int*)d_in[8];

  float* out = (float*)d_out;
  float* idx_out = out;                              // [50][64] as float
  float* log_out = out + (size_t)T_STEPS * BB;       // [50][64][32000]

  uint8_t* wsp = (uint8_t*)d_ws;
  auto alloc = [&](size_t bytes) {
    uint8_t* p = wsp;
    wsp += (bytes + 255) & ~(size_t)255;
    return p;
  };
  float*    hbuf   = (float*)alloc((size_t)2 * BB * HH * 4);
  ushort_t* hhibuf = (ushort_t*)alloc((size_t)2 * BB * HH * 2);
  ushort_t* hlobuf = (ushort_t*)alloc((size_t)2 * BB * HH * 2);
  float*    gi     = (float*)alloc((size_t)BB * G3 * 4);
  float*    gh     = (float*)alloc((size_t)BB * G3 * 4);
  u64*      part   = (u64*)alloc((size_t)BB * NT * 8);
  ushort_t* wihH   = (ushort_t*)alloc((size_t)G3 * DD * 2);
  ushort_t* wihL   = (ushort_t*)alloc((size_t)G3 * DD * 2);
  ushort_t* whhH   = (ushort_t*)alloc((size_t)G3 * HH * 2);
  ushort_t* whhL   = (ushort_t*)alloc((size_t)G3 * HH * 2);
  ushort_t* fcwH   = (ushort_t*)alloc((size_t)VV * HH * 2);
  ushort_t* fcwL   = (ushort_t*)alloc((size_t)VV * HH * 2);

  // capture-safe device/occupancy queries -> legal cooperative grid
  int dev = 0;
  (void)hipGetDevice(&dev);
  int numCU = 0;
  (void)hipDeviceGetAttribute(&numCU, hipDeviceAttributeMultiprocessorCount, dev);
  int occ = 0;
  hipError_t qe = hipOccupancyMaxActiveBlocksPerMultiprocessor(
      &occ, reinterpret_cast<const void*>(&decoder_all), 512, 0);
  long grid = (qe == hipSuccess && numCU > 0) ? (long)occ * (long)numCU : 0;
  if (grid > 512) grid = 512;

  hipError_t err = hipErrorUnknown;
  if (grid >= 64) {
    void* args[] = {&seq, &emb, &Wih, &Whh, &bih, &bhh, &fcw, &fcb, &eos,
                    &idx_out, &log_out, &hbuf, &hhibuf, &hlobuf,
                    &gi, &gh, &part, &wihH, &wihL, &whhH, &whhL, &fcwH, &fcwL};
    err = hipLaunchCooperativeKernel(reinterpret_cast<const void*>(&decoder_all),
                                     dim3((uint32_t)grid), dim3(512), args, 0, stream);
  }
  if (err != hipSuccess) {
    k_pro<<<512, 512, 0, stream>>>(seq, Wih, Whh, fcw, hbuf, hhibuf, hlobuf,
                                   wihH, wihL, whhH, whhL, fcwH, fcwL);
    for (int t = 0; t < T_STEPS; ++t) {
      k_A<<<NMEGA, 512, 0, stream>>>(t, emb, bih, bhh, eos, idx_out,
                                     hbuf, hhibuf, hlobuf, gi, gh, part,
                                     wihH, wihL, whhH, whhL);
      k_B<<<NT, 512, 0, stream>>>(t, hhibuf, hlobuf, fcwH, fcwL, fcb,
                                  log_out, part);
    }
    k_A<<<NMEGA, 512, 0, stream>>>(T_STEPS, emb, bih, bhh, eos, idx_out,
                                   hbuf, hhibuf, hlobuf, gi, gh, part,
                                   wihH, wihL, whhH, whhL);
  }
}

// Round 6
// 14369.971 us; speedup vs baseline: 1.1901x; 1.1901x over previous
//
#include <hip/hip_runtime.h>
#include <hip/hip_cooperative_groups.h>
#include <stdint.h>

namespace cg = cooperative_groups;

#define BB 64
#define DD 512
#define HH 1024
#define VV 32000
#define T_STEPS 50
#define G3 3072
#define NT 500      // logits col-tiles (64 cols each)
#define NMEGA 16    // phase-A mega-blocks (each owns 64 hidden cols)

typedef __attribute__((ext_vector_type(8))) short bf16x8;
typedef __attribute__((ext_vector_type(4))) float f32x4;
typedef unsigned long long u64;
typedef unsigned short ushort_t;

__device__ __forceinline__ uint32_t rotl32(uint32_t x, int d) {
  return (x << d) | (x >> (32 - d));
}

// JAX threefry2x32 (20 rounds) — verified exact in rounds 1-5.
__device__ __forceinline__ void threefry2x32(uint32_t k0, uint32_t k1,
                                             uint32_t& x0, uint32_t& x1) {
  uint32_t ks0 = k0, ks1 = k1, ks2 = k0 ^ k1 ^ 0x1BD11BDAu;
  x0 += ks0; x1 += ks1;
#define TF_R(r) { x0 += x1; x1 = rotl32(x1, (r)); x1 ^= x0; }
  TF_R(13) TF_R(15) TF_R(26) TF_R(6)
  x0 += ks1; x1 += ks2 + 1u;
  TF_R(17) TF_R(29) TF_R(16) TF_R(24)
  x0 += ks2; x1 += ks0 + 2u;
  TF_R(13) TF_R(15) TF_R(26) TF_R(6)
  x0 += ks0; x1 += ks1 + 3u;
  TF_R(17) TF_R(29) TF_R(16) TF_R(24)
  x0 += ks1; x1 += ks2 + 4u;
  TF_R(13) TF_R(15) TF_R(26) TF_R(6)
  x0 += ks2; x1 += ks0 + 5u;
#undef TF_R
}

__device__ __forceinline__ uint32_t f2bf(float f) {
  uint32_t u = __float_as_uint(f);
  return (u + 0x7fffu + ((u >> 16) & 1u)) >> 16;
}
__device__ __forceinline__ float bf2f(uint32_t b) { return __uint_as_float(b << 16); }

__device__ __forceinline__ u64 packkey(float v, int c) {
  uint32_t s = __float_as_uint(v);
  uint32_t mo = (s & 0x80000000u) ? ~s : (s | 0x80000000u);
  return ((u64)mo << 32) | (uint32_t)(~(uint32_t)c);
}
__device__ __forceinline__ u64 umax64(u64 a, u64 b) { return a > b ? a : b; }

union BF8 { uint32_t u[4]; bf16x8 v; };

__device__ __forceinline__ void split8(const float* f, bf16x8& hi, bf16x8& lo) {
  BF8 H, L;
#pragma unroll
  for (int i = 0; i < 4; ++i) {
    float a = f[2 * i], b = f[2 * i + 1];
    uint32_t ha = f2bf(a), hb = f2bf(b);
    float ra = a - bf2f(ha), rb = b - bf2f(hb);
    H.u[i] = ha | (hb << 16);
    L.u[i] = f2bf(ra) | (f2bf(rb) << 16);
  }
  hi = H.v; lo = L.v;
}

__device__ __forceinline__ void split_store4(const float4 v, ushort_t* hi,
                                             ushort_t* lo, long i) {
  uint32_t h0 = f2bf(v.x), h1 = f2bf(v.y), h2 = f2bf(v.z), h3 = f2bf(v.w);
  uint32_t l0 = f2bf(v.x - bf2f(h0)), l1 = f2bf(v.y - bf2f(h1));
  uint32_t l2 = f2bf(v.z - bf2f(h2)), l3 = f2bf(v.w - bf2f(h3));
  *(uint2*)(hi + i) = make_uint2(h0 | (h1 << 16), h2 | (h3 << 16));
  *(uint2*)(lo + i) = make_uint2(l0 | (l1 << 16), l2 | (l3 << 16));
}

__device__ void split_arr(const float* __restrict__ s, ushort_t* __restrict__ hi,
                          ushort_t* __restrict__ lo, long n, long st, long stride) {
  for (long i = st; i < n; i += stride) {
    float4 v = *(const float4*)(s + i);
    split_store4(v, hi, lo, i);
  }
}

// Round-2 proven 256-thread 64x64 tile: LDS-staged B (pre-split bf16 hi/lo),
// padded [64][40] layout, 2x2 wave quadrants, 3-term split-precision MFMA.
// A: pre-split bf16 rows, or fp32 rows gathered via rowidx (AGATHER).
template<bool AGATHER>
__device__ __forceinline__ void tile256(
    ushort_t (*__restrict__ bhS)[40], ushort_t (*__restrict__ blS)[40],
    const ushort_t* __restrict__ Ahi, const ushort_t* __restrict__ Alo,
    const float* __restrict__ Ag, const int* __restrict__ rowidx, int lda,
    const ushort_t* __restrict__ Bhi, const ushort_t* __restrict__ Blo,
    int K, int n0, f32x4 acc[2][2])
{
  const int tid = threadIdx.x, lane = tid & 63, w = tid >> 6;
  const int l15 = lane & 15, q = lane >> 4;
  const int rw = (w >> 1) * 32, cw = (w & 1) * 32;
  const int srow = tid >> 2, schunk = (tid & 3) * 8;

  size_t abase[2];
#pragma unroll
  for (int m = 0; m < 2; ++m) {
    int r = rw + 16 * m + l15;
    abase[m] = (size_t)(AGATHER ? rowidx[r] : r) * lda + 8 * q;
  }
  const size_t bstage = (size_t)(n0 + srow) * K + schunk;

  for (int k0 = 0; k0 < K; k0 += 32) {
    bf16x8 bh8 = *(const bf16x8*)(Bhi + bstage + k0);
    bf16x8 bl8 = *(const bf16x8*)(Blo + bstage + k0);

    bf16x8 ah[2], al[2];
#pragma unroll
    for (int m = 0; m < 2; ++m) {
      if constexpr (AGATHER) {
        const float* ap = Ag + abase[m] + k0;
        float4 a0 = *(const float4*)ap;
        float4 a1 = *(const float4*)(ap + 4);
        float f[8] = {a0.x, a0.y, a0.z, a0.w, a1.x, a1.y, a1.z, a1.w};
        split8(f, ah[m], al[m]);
      } else {
        ah[m] = *(const bf16x8*)(Ahi + abase[m] + k0);
        al[m] = *(const bf16x8*)(Alo + abase[m] + k0);
      }
    }

    __syncthreads();
    *(bf16x8*)&bhS[srow][schunk] = bh8;
    *(bf16x8*)&blS[srow][schunk] = bl8;
    __syncthreads();

    bf16x8 bhf[2], blf[2];
#pragma unroll
    for (int n = 0; n < 2; ++n) {
      bhf[n] = *(const bf16x8*)&bhS[cw + 16 * n + l15][8 * q];
      blf[n] = *(const bf16x8*)&blS[cw + 16 * n + l15][8 * q];
    }
#pragma unroll
    for (int m = 0; m < 2; ++m)
#pragma unroll
      for (int n = 0; n < 2; ++n) {
        acc[m][n] = __builtin_amdgcn_mfma_f32_16x16x32_bf16(ah[m], bhf[n], acc[m][n], 0, 0, 0);
        acc[m][n] = __builtin_amdgcn_mfma_f32_16x16x32_bf16(ah[m], blf[n], acc[m][n], 0, 0, 0);
        acc[m][n] = __builtin_amdgcn_mfma_f32_16x16x32_bf16(al[m], bhf[n], acc[m][n], 0, 0, 0);
      }
  }
}

__device__ __forceinline__ void store_tile256(f32x4 acc[2][2], float* __restrict__ C,
                                              int ldc, int n0)
{
  const int tid = threadIdx.x, lane = tid & 63, w = tid >> 6;
  const int l15 = lane & 15, q = lane >> 4;
  const int rw = (w >> 1) * 32, cw = (w & 1) * 32;
#pragma unroll
  for (int m = 0; m < 2; ++m)
#pragma unroll
    for (int n = 0; n < 2; ++n)
#pragma unroll
      for (int r = 0; r < 4; ++r)
        C[(size_t)(rw + 16 * m + 4 * q + r) * ldc + n0 + cw + 16 * n + l15] = acc[m][n][r];
}

// logits store(+bias) + fused gumbel-argmax -> one atomicMax(u64) per row/block
__device__ __forceinline__ void sample_epi256(
    f32x4 acc[2][2], u64 (*__restrict__ scr)[2],
    const float* __restrict__ bias, float* __restrict__ C, int n0,
    u64* __restrict__ keyWr, int t)
{
  const int tid = threadIdx.x, lane = tid & 63, w = tid >> 6;
  const int l15 = lane & 15, q = lane >> 4;
  const int rw = (w >> 1) * 32, cw = (w & 1) * 32;

  uint32_t kt0 = 0u, kt1 = (uint32_t)t;
  threefry2x32(0u, 42u, kt0, kt1);

  u64 bk[2][4];
#pragma unroll
  for (int m = 0; m < 2; ++m)
#pragma unroll
    for (int r = 0; r < 4; ++r) bk[m][r] = 0ull;

#pragma unroll
  for (int m = 0; m < 2; ++m)
#pragma unroll
    for (int n = 0; n < 2; ++n)
#pragma unroll
      for (int r = 0; r < 4; ++r) {
        int row = rw + 16 * m + 4 * q + r;          // batch index
        int col = n0 + cw + 16 * n + l15;           // vocab index
        float val = acc[m][n][r] + bias[col];
        C[(size_t)row * VV + col] = val;
        uint32_t c0 = 0u, c1 = (uint32_t)(row * VV + col);
        threefry2x32(kt0, kt1, c0, c1);
        uint32_t bits = c0 ^ c1;
        float u = __uint_as_float((bits >> 9) | 0x3f800000u) - 1.0f;
        if (u == 0.0f) u = 1.17549435e-38f;
        float g = -__logf(-__logf(u));
        bk[m][r] = umax64(bk[m][r], packkey(val + g, col));
      }
#pragma unroll
  for (int off = 1; off < 16; off <<= 1)
#pragma unroll
    for (int m = 0; m < 2; ++m)
#pragma unroll
      for (int r = 0; r < 4; ++r)
        bk[m][r] = umax64(bk[m][r], (u64)__shfl_xor((long long)bk[m][r], off, 64));

  if (l15 == 0) {
#pragma unroll
    for (int m = 0; m < 2; ++m)
#pragma unroll
      for (int r = 0; r < 4; ++r)
        scr[rw + 16 * m + 4 * q + r][w & 1] = bk[m][r];
  }
  __syncthreads();
  if (tid < 64)
    atomicMax(&keyWr[tid], umax64(scr[tid][0], scr[tid][1]));
  __syncthreads();
}

// Phase A mega-block mb: read prev-step keys -> idx; zero this step's keys;
// 3 gi tiles (gathered emb rows) + 3 gh tiles; block-local GRU fuse of
// hidden cols [mb*64, mb*64+64).
__device__ __forceinline__ void stepA(
    int mb, int t, const float* __restrict__ emb,
    const float* __restrict__ bih, const float* __restrict__ bhh,
    int eosv, float* __restrict__ idx_out,
    const float* __restrict__ hOld,
    const ushort_t* __restrict__ hhiOld, const ushort_t* __restrict__ hloOld,
    float* __restrict__ hNew,
    ushort_t* __restrict__ hhiNew, ushort_t* __restrict__ hloNew,
    float* __restrict__ gi, float* __restrict__ gh,
    const u64* __restrict__ keyRd, u64* __restrict__ keyWr,
    const ushort_t* __restrict__ wihH, const ushort_t* __restrict__ wihL,
    const ushort_t* __restrict__ whhH, const ushort_t* __restrict__ whhL,
    ushort_t (*__restrict__ bhS)[40], ushort_t (*__restrict__ blS)[40],
    int* __restrict__ idxS)
{
  const int tid = threadIdx.x;
  if (tid < 64) {
    int idx;
    if (t > 0) {
      idx = (int)(~(uint32_t)keyRd[tid]);
      if (mb == 0) idx_out[(size_t)(t - 1) * BB + tid] = (float)idx;
    } else {
      idx = eosv;
    }
    idxS[tid] = idx;
    if (mb == 0 && t < T_STEPS) keyWr[tid] = 0ull;
  }
  __syncthreads();
  if (t == T_STEPS) return;

  const int j0 = mb * 64;
#pragma unroll
  for (int g = 0; g < 3; ++g) {
    f32x4 acc[2][2] = {};
    tile256<true>(bhS, blS, nullptr, nullptr, emb, idxS, DD,
                  wihH, wihL, DD, j0 + g * 1024, acc);
    store_tile256(acc, gi, G3, j0 + g * 1024);
  }
#pragma unroll
  for (int g = 0; g < 3; ++g) {
    f32x4 acc[2][2] = {};
    tile256<false>(bhS, blS, hhiOld, hloOld, nullptr, nullptr, HH,
                   whhH, whhL, HH, j0 + g * 1024, acc);
    store_tile256(acc, gh, G3, j0 + g * 1024);
  }
  __threadfence_block();
  __syncthreads();

  for (int e = tid; e < 64 * 64; e += 256) {
    int b = e >> 6, j = j0 + (e & 63);
    const float* gir = gi + (size_t)b * G3;
    const float* ghr = gh + (size_t)b * G3;
    float ir  = gir[j]        + bih[j],        hr = ghr[j]        + bhh[j];
    float iz  = gir[j + 1024] + bih[j + 1024], hz = ghr[j + 1024] + bhh[j + 1024];
    float in_ = gir[j + 2048] + bih[j + 2048], hn = ghr[j + 2048] + bhh[j + 2048];
    float r = 1.f / (1.f + expf(-(ir + hr)));
    float z = 1.f / (1.f + expf(-(iz + hz)));
    float n = tanhf(in_ + r * hn);
    int i = b * HH + j;
    float hv = (1.f - z) * n + z * hOld[i];
    hNew[i] = hv;
    uint32_t hb = f2bf(hv);
    hhiNew[i] = (ushort_t)hb;
    hloNew[i] = (ushort_t)f2bf(hv - bf2f(hb));
  }
}

__device__ __forceinline__ void stepB(
    int job, int t,
    const ushort_t* __restrict__ hhi, const ushort_t* __restrict__ hlo,
    const ushort_t* __restrict__ fcwH, const ushort_t* __restrict__ fcwL,
    const float* __restrict__ fcb, float* __restrict__ lg,
    u64* __restrict__ keyWr,
    ushort_t (*__restrict__ bhS)[40], ushort_t (*__restrict__ blS)[40],
    u64 (*__restrict__ scr)[2])
{
  f32x4 acc[2][2] = {};
  tile256<false>(bhS, blS, hhi, hlo, nullptr, nullptr, HH,
                 fcwH, fcwL, HH, job * 64, acc);
  sample_epi256(acc, scr, fcb, lg, job * 64, keyWr, t);
}

__device__ __forceinline__ void prologue_body(
    const float* __restrict__ seq, const float* __restrict__ Wih,
    const float* __restrict__ Whh, const float* __restrict__ fcw,
    float* __restrict__ h0, ushort_t* __restrict__ h0hi, ushort_t* __restrict__ h0lo,
    ushort_t* __restrict__ wihH, ushort_t* __restrict__ wihL,
    ushort_t* __restrict__ whhH, ushort_t* __restrict__ whhL,
    ushort_t* __restrict__ fcwH, ushort_t* __restrict__ fcwL)
{
  long st = 4L * ((long)blockIdx.x * blockDim.x + threadIdx.x);
  long stride = 4L * (long)gridDim.x * blockDim.x;
  split_arr(Wih, wihH, wihL, (long)G3 * DD, st, stride);
  split_arr(Whh, whhH, whhL, (long)G3 * HH, st, stride);
  split_arr(fcw, fcwH, fcwL, (long)VV * HH, st, stride);
  for (long i = st; i < BB * HH; i += stride) {
    float4 v = *(const float4*)(seq + i);
    *(float4*)(h0 + i) = v;
    split_store4(v, h0hi, h0lo, i);
  }
}

// ---------------- cooperative mega-kernel ----------------
__global__ __launch_bounds__(256, 4) void decoder_all(
    const float* __restrict__ seq, const float* __restrict__ emb,
    const float* __restrict__ Wih, const float* __restrict__ Whh,
    const float* __restrict__ bih, const float* __restrict__ bhh,
    const float* __restrict__ fcw, const float* __restrict__ fcb,
    const int* __restrict__ eos,
    float* __restrict__ idx_out, float* __restrict__ log_out,
    float* __restrict__ hbuf, ushort_t* __restrict__ hhibuf,
    ushort_t* __restrict__ hlobuf,
    float* __restrict__ gi, float* __restrict__ gh, u64* __restrict__ keybuf,
    ushort_t* __restrict__ wihH, ushort_t* __restrict__ wihL,
    ushort_t* __restrict__ whhH, ushort_t* __restrict__ whhL,
    ushort_t* __restrict__ fcwH, ushort_t* __restrict__ fcwL)
{
  cg::grid_group grid = cg::this_grid();
  __shared__ ushort_t bhS[64][40];
  __shared__ ushort_t blS[64][40];
  __shared__ u64 scr[64][2];
  __shared__ int idxS[64];
  const int bid = blockIdx.x, GRD = gridDim.x;
  const int eosv = eos[0];

  prologue_body(seq, Wih, Whh, fcw, hbuf, hhibuf, hlobuf,
                wihH, wihL, whhH, whhL, fcwH, fcwL);
  grid.sync();

  for (int t = 0; t <= T_STEPS; ++t) {
    const int rb = t & 1, wb = rb ^ 1;
    u64* keyRd = keybuf + (size_t)((t + 1) & 1) * 64;  // prev step's keys
    u64* keyWr = keybuf + (size_t)(t & 1) * 64;        // this step's keys
    for (int mb = bid; mb < NMEGA; mb += GRD)
      stepA(mb, t, emb, bih, bhh, eosv, idx_out,
            hbuf + (size_t)rb * BB * HH,
            hhibuf + (size_t)rb * BB * HH, hlobuf + (size_t)rb * BB * HH,
            hbuf + (size_t)wb * BB * HH,
            hhibuf + (size_t)wb * BB * HH, hlobuf + (size_t)wb * BB * HH,
            gi, gh, keyRd, keyWr, wihH, wihL, whhH, whhL, bhS, blS, idxS);
    if (t == T_STEPS) break;
    grid.sync();
    for (int job = bid; job < NT; job += GRD)
      stepB(job, t, hhibuf + (size_t)wb * BB * HH, hlobuf + (size_t)wb * BB * HH,
            fcwH, fcwL, fcb, log_out + (size_t)t * BB * VV, keyWr,
            bhS, blS, scr);
    grid.sync();
  }
}

// ---------------- multi-launch fallback (same device helpers) ----------------
__global__ __launch_bounds__(256) void k_pro(
    const float* seq, const float* Wih, const float* Whh, const float* fcw,
    float* hbuf, ushort_t* hhibuf, ushort_t* hlobuf,
    ushort_t* wihH, ushort_t* wihL, ushort_t* whhH, ushort_t* whhL,
    ushort_t* fcwH, ushort_t* fcwL)
{
  prologue_body(seq, Wih, Whh, fcw, hbuf, hhibuf, hlobuf,
                wihH, wihL, whhH, whhL, fcwH, fcwL);
}

__global__ __launch_bounds__(256, 4) void k_A(
    int t, const float* emb, const float* bih, const float* bhh,
    const int* eos, float* idx_out,
    float* hbuf, ushort_t* hhibuf, ushort_t* hlobuf,
    float* gi, float* gh, u64* keybuf,
    const ushort_t* wihH, const ushort_t* wihL,
    const ushort_t* whhH, const ushort_t* whhL)
{
  __shared__ ushort_t bhS[64][40];
  __shared__ ushort_t blS[64][40];
  __shared__ int idxS[64];
  const int rb = t & 1, wb = rb ^ 1;
  stepA(blockIdx.x, t, emb, bih, bhh, eos[0], idx_out,
        hbuf + (size_t)rb * BB * HH,
        hhibuf + (size_t)rb * BB * HH, hlobuf + (size_t)rb * BB * HH,
        hbuf + (size_t)wb * BB * HH,
        hhibuf + (size_t)wb * BB * HH, hlobuf + (size_t)wb * BB * HH,
        gi, gh, keybuf + (size_t)((t + 1) & 1) * 64, keybuf + (size_t)(t & 1) * 64,
        wihH, wihL, whhH, whhL, bhS, blS, idxS);
}

__global__ __launch_bounds__(256, 4) void k_B(
    int t, const ushort_t* hhibuf, const ushort_t* hlobuf,
    const ushort_t* fcwH, const ushort_t* fcwL, const float* fcb,
    float* log_out, u64* keybuf)
{
  __shared__ ushort_t bhS[64][40];
  __shared__ ushort_t blS[64][40];
  __shared__ u64 scr[64][2];
  const int wb = (t & 1) ^ 1;
  stepB(blockIdx.x, t, hhibuf + (size_t)wb * BB * HH,
        hlobuf + (size_t)wb * BB * HH, fcwH, fcwL, fcb,
        log_out + (size_t)t * BB * VV, keybuf + (size_t)(t & 1) * 64,
        bhS, blS, scr);
}

extern "C" void kernel_launch(void* const* d_in, const int* in_sizes, int n_in,
                              void* d_out, int out_size, void* d_ws, size_t ws_size,
                              hipStream_t stream) {
  const float* seq = (const float*)d_in[0];
  const float* emb = (const float*)d_in[1];
  const float* Wih = (const float*)d_in[2];
  const float* Whh = (const float*)d_in[3];
  const float* bih = (const float*)d_in[4];
  const float* bhh = (const float*)d_in[5];
  const float* fcw = (const float*)d_in[6];
  const float* fcb = (const float*)d_in[7];
  const int*   eos = (const int*)d_in[8];

  float* out = (float*)d_out;
  float* idx_out = out;                              // [50][64] as float
  float* log_out = out + (size_t)T_STEPS * BB;       // [50][64][32000]

  uint8_t* wsp = (uint8_t*)d_ws;
  auto alloc = [&](size_t bytes) {
    uint8_t* p = wsp;
    wsp += (bytes + 255) & ~(size_t)255;
    return p;
  };
  float*    hbuf   = (float*)alloc((size_t)2 * BB * HH * 4);
  ushort_t* hhibuf = (ushort_t*)alloc((size_t)2 * BB * HH * 2);
  ushort_t* hlobuf = (ushort_t*)alloc((size_t)2 * BB * HH * 2);
  float*    gi     = (float*)alloc((size_t)BB * G3 * 4);
  float*    gh     = (float*)alloc((size_t)BB * G3 * 4);
  u64*      keybuf = (u64*)alloc((size_t)2 * 64 * 8);
  ushort_t* wihH   = (ushort_t*)alloc((size_t)G3 * DD * 2);
  ushort_t* wihL   = (ushort_t*)alloc((size_t)G3 * DD * 2);
  ushort_t* whhH   = (ushort_t*)alloc((size_t)G3 * HH * 2);
  ushort_t* whhL   = (ushort_t*)alloc((size_t)G3 * HH * 2);
  ushort_t* fcwH   = (ushort_t*)alloc((size_t)VV * HH * 2);
  ushort_t* fcwL   = (ushort_t*)alloc((size_t)VV * HH * 2);

  // capture-safe device/occupancy queries -> legal cooperative grid
  int dev = 0;
  (void)hipGetDevice(&dev);
  int numCU = 0;
  (void)hipDeviceGetAttribute(&numCU, hipDeviceAttributeMultiprocessorCount, dev);
  int occ = 0;
  hipError_t qe = hipOccupancyMaxActiveBlocksPerMultiprocessor(
      &occ, reinterpret_cast<const void*>(&decoder_all), 256, 0);
  long grid = (qe == hipSuccess && numCU > 0) ? (long)occ * (long)numCU : 0;
  if (grid > 512) grid = 512;

  hipError_t err = hipErrorUnknown;
  if (grid >= 64) {
    void* args[] = {&seq, &emb, &Wih, &Whh, &bih, &bhh, &fcw, &fcb, &eos,
                    &idx_out, &log_out, &hbuf, &hhibuf, &hlobuf,
                    &gi, &gh, &keybuf, &wihH, &wihL, &whhH, &whhL, &fcwH, &fcwL};
    err = hipLaunchCooperativeKernel(reinterpret_cast<const void*>(&decoder_all),
                                     dim3((uint32_t)grid), dim3(256), args, 0, stream);
  }
  if (err != hipSuccess) {
    k_pro<<<512, 256, 0, stream>>>(seq, Wih, Whh, fcw, hbuf, hhibuf, hlobuf,
                                   wihH, wihL, whhH, whhL, fcwH, fcwL);
    for (int t = 0; t < T_STEPS; ++t) {
      k_A<<<NMEGA, 256, 0, stream>>>(t, emb, bih, bhh, eos, idx_out,
                                     hbuf, hhibuf, hlobuf, gi, gh, keybuf,
                                     wihH, wihL, whhH, whhL);
      k_B<<<NT, 256, 0, stream>>>(t, hhibuf, hlobuf, fcwH, fcwL, fcb,
                                  log_out, keybuf);
    }
    k_A<<<NMEGA, 256, 0, stream>>>(T_STEPS, emb, bih, bhh, eos, idx_out,
                                   hbuf, hhibuf, hlobuf, gi, gh, keybuf,
                                   wihH, wihL, whhH, whhL);
  }
}